// Round 5
// baseline (871.918 us; speedup 1.0000x reference)
//
#include <hip/hip_runtime.h>

// Problem constants: B=4, De=Do=64, T=4, H=W=128, PATCH=7, R=3
#define ATTN_OFF 4194304                 // B*Do*H*W (mem region size in floats)
// packed attn ws: [b][G=256][t][13][64] float4  = 3,407,872 float4s
#define WS_F4_COUNT 3407872ull

// ---------------------------------------------------------------------------
// K1 v5: correlation logits, software-pipelined.
//  - 2 vertical pixels/thread (tile 32x16), 8-row shared window.
//  - Alternating LDS buffer, ONE barrier per chunk:
//      [issue loads for cc+1] [compute cc] [scale+write cc+1 -> buf^1] [bar]
//  - Staging decomposition (quad,y,xi, clamped goff, LDS off, border mask)
//    is chunk-invariant -> precomputed ONCE (no per-chunk magic-muls).
//  - In-flight chunk = 7 named float4 (28 VGPR); q prefetch = 32 VGPR
//    rotating. No lambdas, no runtime-indexed arrays (anti-spill, cf. R2).
//  - Border handling: load from clamped address, multiply by {0,1} mask ->
//    exact zeros, numerics identical (channel order unchanged).
// ---------------------------------------------------------------------------
__global__ __launch_bounds__(256, 2) void k1_corr(
    const float* __restrict__ m_in, const float* __restrict__ q_in,
    float* __restrict__ out)
{
  const int b = blockIdx.z >> 2, t = blockIdx.z & 3;
  const int h0 = blockIdx.y * 16, w0 = blockIdx.x * 32;
  const int tid = threadIdx.x;
  const int tx = tid & 31, ty = tid >> 5;

  // [buf][quad][y 0..21][x 0..41][c%4]; slot xi+1 <-> gx = w0-3+xi
  __shared__ float m_s[2][2][22][42][4];   // 59,136 B (2 blocks/CU ok)
  float* const lds0 = &m_s[0][0][0][0][0];

  float acc0[49], acc1[49];
#pragma unroll
  for (int d = 0; d < 49; ++d) { acc0[d] = 0.f; acc1[d] = 0.f; }

  // ---- chunk-invariant staging decomposition (items: 2q x 22y x 38xi = 1672)
  // k=0..5: item = tid+256k < 1536 always active; k=6 active iff tid < 136.
  int   goff[7];   // clamped offset within 4-channel stream
  int   loff[7];   // float offset within one LDS buffer
  float msk[7];    // 1.0 in-bounds else 0.0
#pragma unroll
  for (int k = 0; k < 7; ++k) {
    const int item = tid + (k << 8);
    const int quad = item >= 836 ? 1 : 0;
    const int rem  = item - 836 * quad;
    const int y  = rem / 38;                  // magic-mul, once per kernel
    const int xi = rem - 38 * y;
    const int gy = h0 - 3 + y, gx = w0 - 3 + xi;
    const bool inb = ((unsigned)gy < 128u) && ((unsigned)gx < 128u);
    const int gyc = gy < 0 ? 0 : (gy > 127 ? 127 : gy);
    const int gxc = gx < 0 ? 0 : (gx > 127 ? 127 : gx);
    goff[k] = (quad << 18) + (gyc << 7) + gxc;   // quad stride = 4ch*4t*16384
    loff[k] = quad * 3696 + y * 168 + (xi + 1) * 4;
    msk[k]  = inb ? 1.f : 0.f;
  }

  const int qpix = ((h0 + 2 * ty) << 7) + w0 + tx;   // pixel0; pixel1 = +128

  // ---- prologue: stage chunk 0 into buf 0, prefetch q for chunk 0 ----
  float qa[8], qb[8];                       // current-chunk q (2cq x 4ch)
  {
    const float* base = m_in + ((b * 256 + t) << 14);
    float4 v0, v1, v2, v3, v4, v5, v6;
    const float* p;
    p = base + goff[0]; v0.x = p[0]; v0.y = p[65536]; v0.z = p[131072]; v0.w = p[196608];
    p = base + goff[1]; v1.x = p[0]; v1.y = p[65536]; v1.z = p[131072]; v1.w = p[196608];
    p = base + goff[2]; v2.x = p[0]; v2.y = p[65536]; v2.z = p[131072]; v2.w = p[196608];
    p = base + goff[3]; v3.x = p[0]; v3.y = p[65536]; v3.z = p[131072]; v3.w = p[196608];
    p = base + goff[4]; v4.x = p[0]; v4.y = p[65536]; v4.z = p[131072]; v4.w = p[196608];
    p = base + goff[5]; v5.x = p[0]; v5.y = p[65536]; v5.z = p[131072]; v5.w = p[196608];
    v6 = make_float4(0.f, 0.f, 0.f, 0.f);
    if (tid < 136) {
      p = base + goff[6]; v6.x = p[0]; v6.y = p[65536]; v6.z = p[131072]; v6.w = p[196608];
    }
#pragma unroll
    for (int k = 0; k < 8; ++k) {
      const float* qp = q_in + ((b * 64 + k) << 14) + qpix;   // ch k of chunk 0
      qa[k] = qp[0];
      qb[k] = qp[128];
    }
    *(float4*)(lds0 + loff[0]) = make_float4(v0.x*msk[0], v0.y*msk[0], v0.z*msk[0], v0.w*msk[0]);
    *(float4*)(lds0 + loff[1]) = make_float4(v1.x*msk[1], v1.y*msk[1], v1.z*msk[1], v1.w*msk[1]);
    *(float4*)(lds0 + loff[2]) = make_float4(v2.x*msk[2], v2.y*msk[2], v2.z*msk[2], v2.w*msk[2]);
    *(float4*)(lds0 + loff[3]) = make_float4(v3.x*msk[3], v3.y*msk[3], v3.z*msk[3], v3.w*msk[3]);
    *(float4*)(lds0 + loff[4]) = make_float4(v4.x*msk[4], v4.y*msk[4], v4.z*msk[4], v4.w*msk[4]);
    *(float4*)(lds0 + loff[5]) = make_float4(v5.x*msk[5], v5.y*msk[5], v5.z*msk[5], v5.w*msk[5]);
    if (tid < 136)
      *(float4*)(lds0 + loff[6]) = make_float4(v6.x*msk[6], v6.y*msk[6], v6.z*msk[6], v6.w*msk[6]);
  }
  __syncthreads();

#pragma unroll 1
  for (int cc = 0; cc < 8; ++cc) {          // 8-channel chunks
    const int buf = cc & 1;

    // ---- issue next chunk's loads (no waits; consumed after compute) ----
    float4 n0, n1, n2, n3, n4, n5, n6;
    float qan[8], qbn[8];
    if (cc < 7) {
      const float* base = m_in + (((b * 64 + (cc + 1) * 8) * 4 + t) << 14);
      const float* p;
      p = base + goff[0]; n0.x = p[0]; n0.y = p[65536]; n0.z = p[131072]; n0.w = p[196608];
      p = base + goff[1]; n1.x = p[0]; n1.y = p[65536]; n1.z = p[131072]; n1.w = p[196608];
      p = base + goff[2]; n2.x = p[0]; n2.y = p[65536]; n2.z = p[131072]; n2.w = p[196608];
      p = base + goff[3]; n3.x = p[0]; n3.y = p[65536]; n3.z = p[131072]; n3.w = p[196608];
      p = base + goff[4]; n4.x = p[0]; n4.y = p[65536]; n4.z = p[131072]; n4.w = p[196608];
      p = base + goff[5]; n5.x = p[0]; n5.y = p[65536]; n5.z = p[131072]; n5.w = p[196608];
      n6 = make_float4(0.f, 0.f, 0.f, 0.f);
      if (tid < 136) {
        p = base + goff[6]; n6.x = p[0]; n6.y = p[65536]; n6.z = p[131072]; n6.w = p[196608];
      }
#pragma unroll
      for (int k = 0; k < 8; ++k) {
        const float* qp = q_in + ((b * 64 + (cc + 1) * 8 + k) << 14) + qpix;
        qan[k] = qp[0];
        qbn[k] = qp[128];
      }
    }

    // ---- compute on buf (q already in registers) ----
#pragma unroll
    for (int cq = 0; cq < 2; ++cq) {
#pragma unroll
      for (int wr = 0; wr < 8; ++wr) {      // shared 8-row window, 2 pixels
        const float4* rowp = (const float4*)&m_s[buf][cq][2 * ty + wr][tx + 1][0];
#pragma unroll
        for (int dx = 0; dx < 7; ++dx) {
          const float4 mv = rowp[dx];
          if (wr < 7)
            acc0[wr * 7 + dx] += qa[cq*4+0]*mv.x + qa[cq*4+1]*mv.y
                               + qa[cq*4+2]*mv.z + qa[cq*4+3]*mv.w;
          if (wr > 0)
            acc1[(wr - 1) * 7 + dx] += qb[cq*4+0]*mv.x + qb[cq*4+1]*mv.y
                                     + qb[cq*4+2]*mv.z + qb[cq*4+3]*mv.w;
        }
      }
    }

    // ---- scale + write next chunk into buf^1, rotate q ----
    if (cc < 7) {
      float* lb = lds0 + (buf ^ 1) * 7392;
      *(float4*)(lb + loff[0]) = make_float4(n0.x*msk[0], n0.y*msk[0], n0.z*msk[0], n0.w*msk[0]);
      *(float4*)(lb + loff[1]) = make_float4(n1.x*msk[1], n1.y*msk[1], n1.z*msk[1], n1.w*msk[1]);
      *(float4*)(lb + loff[2]) = make_float4(n2.x*msk[2], n2.y*msk[2], n2.z*msk[2], n2.w*msk[2]);
      *(float4*)(lb + loff[3]) = make_float4(n3.x*msk[3], n3.y*msk[3], n3.z*msk[3], n3.w*msk[3]);
      *(float4*)(lb + loff[4]) = make_float4(n4.x*msk[4], n4.y*msk[4], n4.z*msk[4], n4.w*msk[4]);
      *(float4*)(lb + loff[5]) = make_float4(n5.x*msk[5], n5.y*msk[5], n5.z*msk[5], n5.w*msk[5]);
      if (tid < 136)
        *(float4*)(lb + loff[6]) = make_float4(n6.x*msk[6], n6.y*msk[6], n6.z*msk[6], n6.w*msk[6]);
#pragma unroll
      for (int k = 0; k < 8; ++k) { qa[k] = qan[k]; qb[k] = qbn[k]; }
    }
    __syncthreads();
  }

  const int obase = ATTN_OFF + ((b * 196 + t) << 14)
                  + ((h0 + 2 * ty) << 7) + w0 + tx;
#pragma unroll
  for (int d = 0; d < 49; ++d) {
    out[obase +       ((d * 4) << 14)] = acc0[d];
    out[obase + 128 + ((d * 4) << 14)] = acc1[d];
  }
}

// ---------------------------------------------------------------------------
// K2: softmax (unchanged) + packed-attn write into d_ws.
// Packed layout keyed to k3's wave tiling: G = (h>>1)*4 + (w>>5),
// lane = (h&1)*32 + (w&31); element (b,G,t,g,lane) at
// ((b*256+G)*4+t)*13*64 + g*64 + lane   (float4 units, d = 4g+j).
// ---------------------------------------------------------------------------
__global__ __launch_bounds__(256) void k2_softmax(
    float* __restrict__ out, const float* __restrict__ cst,
    float4* __restrict__ ws)
{
  const int tid = threadIdx.x;
  const int pl = tid & 63;             // pixel within block
  const int t  = tid >> 6;
  const int pix = blockIdx.x * 64 + pl;      // 65536 pixels total
  const int b = pix >> 14, hw = pix & 16383;
  float* base = out + ATTN_OFF + ((b * 196 + t) << 14) + hw;

  float v[49];
#pragma unroll
  for (int d = 0; d < 49; ++d) v[d] = base[(d * 4) << 14];

  float mx = -1e30f;
#pragma unroll
  for (int d = 0; d < 49; ++d) mx = fmaxf(mx, v[d]);

  __shared__ float red[4][64];
  red[t][pl] = mx;
  __syncthreads();
  float M = fmaxf(fmaxf(red[0][pl], red[1][pl]), fmaxf(red[2][pl], red[3][pl]));
  M = fmaxf(M, cst[0]);
  __syncthreads();

  float s = 0.f;
#pragma unroll
  for (int d = 0; d < 49; ++d) { v[d] = __expf(v[d] - M); s += v[d]; }
  red[t][pl] = s;
  __syncthreads();
  const float l = red[0][pl] + red[1][pl] + red[2][pl] + red[3][pl]
                + __expf(cst[0] - M);
  const float inv = 1.f / l;
#pragma unroll
  for (int d = 0; d < 49; ++d) {
    const float r = v[d] * inv;
    base[(d * 4) << 14] = r;           // reference-layout output (validated)
    v[d] = r;
  }

  if (ws) {
    const int h = hw >> 7, wc = hw & 127;
    const int G    = ((h >> 1) << 2) + (wc >> 5);
    const int lane = ((h & 1) << 5) + (wc & 31);
    float4* dst = ws + (size_t)(((b * 256 + G) * 4 + t) * 13) * 64 + lane;
#pragma unroll
    for (int g = 0; g < 13; ++g) {
      float4 p;
      p.x = v[g * 4];
      p.y = (g < 12) ? v[g * 4 + 1] : 0.f;
      p.z = (g < 12) ? v[g * 4 + 2] : 0.f;
      p.w = (g < 12) ? v[g * 4 + 3] : 0.f;
      dst[g * 64] = p;
    }
  }
}

// ---------------------------------------------------------------------------
// K3 v4 (FROZEN, ~45 us): high-occupancy 1-pixel/thread structure
// (tile 32x8, 16 ch/block, 1024 blocks, 37.6 KB LDS -> 4 blocks/CU),
// conflict-free immediate-write staging + g-pipelined coalesced ws reads.
// Near its LDS-pipe floor (~42 us).
// ---------------------------------------------------------------------------
__global__ __launch_bounds__(256) void k3_read_ws(
    const float* __restrict__ m_out, float* __restrict__ out,
    const float4* __restrict__ ws)
{
  const int b = blockIdx.z >> 2, cq = blockIdx.z & 3;
  const int h0 = blockIdx.y * 8, w0 = blockIdx.x * 32;
  const int tid = threadIdx.x;
  const int tx = tid & 31, ty = tid >> 5;
  const int h = h0 + ty, w = w0 + tx;
  const int waveid = tid >> 6, lane = tid & 63;
  const int G = ((h0 >> 1) + waveid) * 4 + blockIdx.x;

  __shared__ float m_s[4][14][42][4];  // 37,632 B

  float acc[16];
#pragma unroll
  for (int i = 0; i < 16; ++i) acc[i] = 0.f;

#pragma unroll 1
  for (int t = 0; t < 4; ++t) {
    const float4* ap = ws + (size_t)(((b * 256 + G) * 4 + t) * 13) * 64 + lane;

    __syncthreads();                   // prev iter's reads complete
    {
      // 2128 items = 4 quads x 14 rows x 38 xi ; load -> immediate b128 write
      const float* base = m_out + (((b * 64 + cq * 16) * 4 + t) << 14);
#pragma unroll
      for (int k = 0; k < 9; ++k) {
        const int item = tid + (k << 8);
        if (item < 2128) {
          const int quad = item / 532;       // 532 = 14*38
          const int rem  = item - 532 * quad;
          const int y  = rem / 38;
          const int xi = rem - 38 * y;
          const int gy = h0 - 3 + y, gx = w0 - 3 + xi;
          float4 v = make_float4(0.f, 0.f, 0.f, 0.f);
          if ((unsigned)gy < 128u && (unsigned)gx < 128u) {
            const float* p = base + (quad << 18) + (gy << 7) + gx;
            v.x = p[0];
            v.y = p[1 << 16];
            v.z = p[2 << 16];
            v.w = p[3 << 16];
          }
          *(float4*)&m_s[quad][y][xi + 1][0] = v;
        }
      }
    }
    __syncthreads();

    float4 cur = ap[0];
#pragma unroll
    for (int g = 0; g < 13; ++g) {
      float4 nxt = cur;
      if (g < 12) nxt = ap[(g + 1) * 64];
#pragma unroll
      for (int j = 0; j < 4; ++j) {
        const int d = g * 4 + j;
        if (d >= 49) break;
        const int dy = d / 7, dx = d % 7;
        const float av = (j == 0) ? cur.x : (j == 1) ? cur.y
                       : (j == 2) ? cur.z : cur.w;
#pragma unroll
        for (int q = 0; q < 4; ++q) {
          const float4 mv = *(const float4*)&m_s[q][ty + dy][tx + dx + 1][0];
          acc[q * 4 + 0] += av * mv.x;
          acc[q * 4 + 1] += av * mv.y;
          acc[q * 4 + 2] += av * mv.z;
          acc[q * 4 + 3] += av * mv.w;
        }
      }
      cur = nxt;
    }
  }

#pragma unroll
  for (int q = 0; q < 4; ++q)
#pragma unroll
    for (int k = 0; k < 4; ++k)
      out[((b * 64 + cq * 16 + q * 4 + k) << 14) + (h << 7) + w] = acc[q * 4 + k];
}

// ---------------------------------------------------------------------------
// K3 fallback (unchanged) — used only if ws_size is too small.
// ---------------------------------------------------------------------------
__global__ __launch_bounds__(256) void k3_read_fb(
    const float* __restrict__ m_out, float* __restrict__ out)
{
  const int b = blockIdx.z >> 2, cq = blockIdx.z & 3;
  const int h0 = blockIdx.y * 8, w0 = blockIdx.x * 32;
  const int tid = threadIdx.x;
  const int tx = tid & 31, ty = tid >> 5;
  const int h = h0 + ty, w = w0 + tx;

  __shared__ float m_s[4][14][38][4];
  const float* __restrict__ attn = out + ATTN_OFF;

  float acc[16];
#pragma unroll
  for (int i = 0; i < 16; ++i) acc[i] = 0.f;

#pragma unroll 1
  for (int t = 0; t < 4; ++t) {
    float a[49];
#pragma unroll
    for (int d = 0; d < 49; ++d)
      a[d] = attn[((b * 196 + d * 4 + t) << 14) + (h << 7) + w];

    __syncthreads();
    for (int e = tid; e < 8512; e += 256) {
      int c16 = e / 532; int rem = e - c16 * 532;
      int y = rem / 38;  int x = rem - y * 38;
      int gy = h0 - 3 + y, gx = w0 - 3 + x;
      float v = 0.f;
      if (gy >= 0 && gy < 128 && gx >= 0 && gx < 128)
        v = m_out[(((b * 64 + cq * 16 + c16) * 4 + t) << 14) + (gy << 7) + gx];
      m_s[c16 >> 2][y][x][c16 & 3] = v;
    }
    __syncthreads();

#pragma unroll
    for (int dy = 0; dy < 7; ++dy)
#pragma unroll
      for (int dx = 0; dx < 7; ++dx) {
        const float av = a[dy * 7 + dx];
#pragma unroll
        for (int q = 0; q < 4; ++q) {
          const float4 mv = *(const float4*)&m_s[q][ty + dy][tx + dx][0];
          acc[q * 4 + 0] += av * mv.x;
          acc[q * 4 + 1] += av * mv.y;
          acc[q * 4 + 2] += av * mv.z;
          acc[q * 4 + 3] += av * mv.w;
        }
      }
  }

#pragma unroll
  for (int q = 0; q < 4; ++q)
#pragma unroll
    for (int k = 0; k < 4; ++k)
      out[((b * 64 + cq * 16 + q * 4 + k) << 14) + (h << 7) + w] = acc[q * 4 + k];
}

extern "C" void kernel_launch(void* const* d_in, const int* in_sizes, int n_in,
                              void* d_out, int out_size, void* d_ws, size_t ws_size,
                              hipStream_t stream) {
  const float* m_in  = (const float*)d_in[0];
  const float* m_out = (const float*)d_in[1];
  const float* q_in  = (const float*)d_in[2];
  const float* cst   = (const float*)d_in[3];
  float* out = (float*)d_out;

  const bool use_ws = (ws_size >= WS_F4_COUNT * 16ull) && d_ws != nullptr;
  float4* ws = use_ws ? (float4*)d_ws : nullptr;

  k1_corr<<<dim3(4, 8, 16), dim3(256), 0, stream>>>(m_in, q_in, out);
  k2_softmax<<<dim3(1024), dim3(256), 0, stream>>>(out, cst, ws);
  if (use_ws)
    k3_read_ws<<<dim3(4, 16, 16), dim3(256), 0, stream>>>(m_out, out, ws);
  else
    k3_read_fb<<<dim3(4, 16, 16), dim3(256), 0, stream>>>(m_out, out);
}

// Round 6
// 203.377 us; speedup vs baseline: 4.2872x; 4.2872x over previous
//
#include <hip/hip_runtime.h>

// Problem constants: B=4, De=Do=64, T=4, H=W=128, PATCH=7, R=3
#define ATTN_OFF 4194304                 // B*Do*H*W (mem region size in floats)
// packed attn ws region: [b][G=256][t][13][64] float4 = 3,407,872 float4s
#define WS_F4_COUNT 3407872ull
// ws map (float4 units):
//   [0, WS)          : packed attn (k2 -> k3)
//   [WS, 2WS)        : k1 partial logits, channels 0..31   (packed layout)
//   [2WS, 3WS)       : k1 partial logits, channels 32..63  (packed layout)

// ---------------------------------------------------------------------------
// K1 split (v6): correlation logits over HALF the channels per block.
//  - grid (4,8,32): z = b*8 + half*4 + t -> 1024 blocks = 4/CU co-resident
//    (R4's 512 blocks = 2/CU left global latency exposed; R2/R5 showed
//    register-pipelining spills, so we hide latency with occupancy instead).
//  - per block: 2 vertical px/thread (tile 32x16), 8-row shared window,
//    single LDS buffer, conflict-free immediate-write staging (R4-proven).
//  - output: packed float4 partials into ws (coalesced b128 stores),
//    layout identical to the k2->k3 packed region, one region per half.
// ---------------------------------------------------------------------------
__global__ __launch_bounds__(256, 2) void k1_corr_split(
    const float* __restrict__ m_in, const float* __restrict__ q_in,
    float4* __restrict__ ws)
{
  const int b = blockIdx.z >> 3, half = (blockIdx.z >> 2) & 1, t = blockIdx.z & 3;
  const int h0 = blockIdx.y * 16, w0 = blockIdx.x * 32;
  const int tid = threadIdx.x;
  const int tx = tid & 31, ty = tid >> 5;

  // [c-quad][y 0..21][x 0..41][c%4]; slot xi+1 <-> gx = w0-3+xi
  __shared__ float m_s[2][22][42][4];   // 29,568 B

  float acc0[49], acc1[49];
#pragma unroll
  for (int d = 0; d < 49; ++d) { acc0[d] = 0.f; acc1[d] = 0.f; }

#pragma unroll 1
  for (int cc = 0; cc < 4; ++cc) {          // 4 chunks x 8 channels
    const int cbase = half * 32 + cc * 8;
    __syncthreads();                        // prev chunk's reads complete
    {
      // 1672 items = 2 quads x 22 rows x 38 xi ; load -> immediate b128 write
      const float* base = m_in + (((b * 64 + cbase) * 4 + t) << 14);
#pragma unroll
      for (int k = 0; k < 7; ++k) {
        const int item = tid + (k << 8);
        if (item < 1672) {
          const int quad = item >= 836;
          const int rem  = item - 836 * quad;
          const int y  = rem / 38;             // magic-mul
          const int xi = rem - 38 * y;
          const int gy = h0 - 3 + y, gx = w0 - 3 + xi;
          float4 v = make_float4(0.f, 0.f, 0.f, 0.f);
          if ((unsigned)gy < 128u && (unsigned)gx < 128u) {
            const float* p = base + (quad << 18) + (gy << 7) + gx;
            v.x = p[0];
            v.y = p[1 << 16];
            v.z = p[2 << 16];
            v.w = p[3 << 16];
          }
          *(float4*)&m_s[quad][y][xi + 1][0] = v;
        }
      }
    }
    __syncthreads();

#pragma unroll
    for (int cq = 0; cq < 2; ++cq) {
      float q0[4], q1[4];
#pragma unroll
      for (int k = 0; k < 4; ++k) {
        const float* qp = q_in + ((b * 64 + cbase + cq * 4 + k) << 14)
                        + ((h0 + 2 * ty) << 7) + w0 + tx;
        q0[k] = qp[0];
        q1[k] = qp[128];
      }
#pragma unroll
      for (int wr = 0; wr < 8; ++wr) {      // shared 8-row window, 2 pixels
        const float4* rowp = (const float4*)&m_s[cq][2 * ty + wr][tx + 1][0];
#pragma unroll
        for (int dx = 0; dx < 7; ++dx) {
          const float4 mv = rowp[dx];
          if (wr < 7)
            acc0[wr * 7 + dx] += q0[0]*mv.x + q0[1]*mv.y + q0[2]*mv.z + q0[3]*mv.w;
          if (wr > 0)
            acc1[(wr - 1) * 7 + dx] += q1[0]*mv.x + q1[1]*mv.y + q1[2]*mv.z + q1[3]*mv.w;
        }
      }
    }
  }

  // packed partial store: G = (h>>1)*4 + (w>>5); lane = (h&1)*32 + (w&31).
  // px0 (h even) -> lane tx; px1 -> lane tx+32. g=12 padded with zeros.
  const int G = ((h0 >> 1) + ty) * 4 + blockIdx.x;
  float4* dst = ws + WS_F4_COUNT * (1 + half)
              + (size_t)(((b * 256 + G) * 4 + t) * 13) * 64 + tx;
#pragma unroll
  for (int g = 0; g < 13; ++g) {
    float4 p0, p1;
    p0.x = acc0[g * 4];
    p1.x = acc1[g * 4];
    p0.y = (g < 12) ? acc0[g * 4 + 1] : 0.f;
    p0.z = (g < 12) ? acc0[g * 4 + 2] : 0.f;
    p0.w = (g < 12) ? acc0[g * 4 + 3] : 0.f;
    p1.y = (g < 12) ? acc1[g * 4 + 1] : 0.f;
    p1.z = (g < 12) ? acc1[g * 4 + 2] : 0.f;
    p1.w = (g < 12) ? acc1[g * 4 + 3] : 0.f;
    dst[g * 64]      = p0;
    dst[g * 64 + 32] = p1;
  }
}

// ---------------------------------------------------------------------------
// K2 split: read both packed partial regions (coalesced b128), add, softmax,
// write attn in reference layout (required output) + packed attn for k3.
// ---------------------------------------------------------------------------
__global__ __launch_bounds__(256) void k2_softmax_split(
    float* __restrict__ out, const float* __restrict__ cst,
    float4* __restrict__ ws)
{
  const int tid = threadIdx.x;
  const int pl = tid & 63;             // pixel within block
  const int t  = tid >> 6;
  const int pix = blockIdx.x * 64 + pl;      // 65536 pixels total
  const int b = pix >> 14, hw = pix & 16383;
  float* base = out + ATTN_OFF + ((b * 196 + t) << 14) + hw;

  const int h = hw >> 7, wc = hw & 127;
  const int G    = ((h >> 1) << 2) + (wc >> 5);
  const int lane = ((h & 1) << 5) + (wc & 31);
  const size_t idx = (size_t)(((b * 256 + G) * 4 + t) * 13) * 64 + lane;
  const float4* p0 = ws + WS_F4_COUNT + idx;
  const float4* p1 = ws + 2 * WS_F4_COUNT + idx;

  float v[49];
#pragma unroll
  for (int g = 0; g < 13; ++g) {
    const float4 a = p0[g * 64];
    const float4 c = p1[g * 64];
    v[g * 4] = a.x + c.x;
    if (g < 12) {
      v[g * 4 + 1] = a.y + c.y;
      v[g * 4 + 2] = a.z + c.z;
      v[g * 4 + 3] = a.w + c.w;
    }
  }

  float mx = -1e30f;
#pragma unroll
  for (int d = 0; d < 49; ++d) mx = fmaxf(mx, v[d]);

  __shared__ float red[4][64];
  red[t][pl] = mx;
  __syncthreads();
  float M = fmaxf(fmaxf(red[0][pl], red[1][pl]), fmaxf(red[2][pl], red[3][pl]));
  M = fmaxf(M, cst[0]);
  __syncthreads();

  float s = 0.f;
#pragma unroll
  for (int d = 0; d < 49; ++d) { v[d] = __expf(v[d] - M); s += v[d]; }
  red[t][pl] = s;
  __syncthreads();
  const float l = red[0][pl] + red[1][pl] + red[2][pl] + red[3][pl]
                + __expf(cst[0] - M);
  const float inv = 1.f / l;

  float4* dst = ws + idx;
#pragma unroll
  for (int g = 0; g < 13; ++g) {
    float4 p;
    p.x = v[g * 4] * inv;
    base[((g * 16) << 14)] = p.x;            // reference-layout attn output
    p.y = p.z = p.w = 0.f;
    if (g < 12) {
      p.y = v[g * 4 + 1] * inv;
      p.z = v[g * 4 + 2] * inv;
      p.w = v[g * 4 + 3] * inv;
      base[(((g * 4 + 1) * 4) << 14)] = p.y;
      base[(((g * 4 + 2) * 4) << 14)] = p.z;
      base[(((g * 4 + 3) * 4) << 14)] = p.w;
    }
    dst[g * 64] = p;                         // packed attn for k3
  }
}

// ---------------------------------------------------------------------------
// K1 fallback (R4 v4, proven): full 64-channel blocks, strided logit stores.
// Used only when ws is too small for the split regions.
// ---------------------------------------------------------------------------
__global__ __launch_bounds__(256, 2) void k1_corr(
    const float* __restrict__ m_in, const float* __restrict__ q_in,
    float* __restrict__ out)
{
  const int b = blockIdx.z >> 2, t = blockIdx.z & 3;
  const int h0 = blockIdx.y * 16, w0 = blockIdx.x * 32;
  const int tid = threadIdx.x;
  const int tx = tid & 31, ty = tid >> 5;

  __shared__ float m_s[2][22][42][4];   // 29,568 B

  float acc0[49], acc1[49];
#pragma unroll
  for (int d = 0; d < 49; ++d) { acc0[d] = 0.f; acc1[d] = 0.f; }

#pragma unroll 1
  for (int cc = 0; cc < 8; ++cc) {
    __syncthreads();
    {
      const float* base = m_in + (((b * 64 + cc * 8) * 4 + t) << 14);
#pragma unroll
      for (int k = 0; k < 7; ++k) {
        const int item = tid + (k << 8);
        if (item < 1672) {
          const int quad = item >= 836;
          const int rem  = item - 836 * quad;
          const int y  = rem / 38;
          const int xi = rem - 38 * y;
          const int gy = h0 - 3 + y, gx = w0 - 3 + xi;
          float4 v = make_float4(0.f, 0.f, 0.f, 0.f);
          if ((unsigned)gy < 128u && (unsigned)gx < 128u) {
            const float* p = base + (quad << 18) + (gy << 7) + gx;
            v.x = p[0];
            v.y = p[1 << 16];
            v.z = p[2 << 16];
            v.w = p[3 << 16];
          }
          *(float4*)&m_s[quad][y][xi + 1][0] = v;
        }
      }
    }
    __syncthreads();

#pragma unroll
    for (int cq = 0; cq < 2; ++cq) {
      float q0[4], q1[4];
#pragma unroll
      for (int k = 0; k < 4; ++k) {
        const float* qp = q_in + ((b * 64 + cc * 8 + cq * 4 + k) << 14)
                        + ((h0 + 2 * ty) << 7) + w0 + tx;
        q0[k] = qp[0];
        q1[k] = qp[128];
      }
#pragma unroll
      for (int wr = 0; wr < 8; ++wr) {
        const float4* rowp = (const float4*)&m_s[cq][2 * ty + wr][tx + 1][0];
#pragma unroll
        for (int dx = 0; dx < 7; ++dx) {
          const float4 mv = rowp[dx];
          if (wr < 7)
            acc0[wr * 7 + dx] += q0[0]*mv.x + q0[1]*mv.y + q0[2]*mv.z + q0[3]*mv.w;
          if (wr > 0)
            acc1[(wr - 1) * 7 + dx] += q1[0]*mv.x + q1[1]*mv.y + q1[2]*mv.z + q1[3]*mv.w;
        }
      }
    }
  }

  const int obase = ATTN_OFF + ((b * 196 + t) << 14)
                  + ((h0 + 2 * ty) << 7) + w0 + tx;
#pragma unroll
  for (int d = 0; d < 49; ++d) {
    out[obase +       ((d * 4) << 14)] = acc0[d];
    out[obase + 128 + ((d * 4) << 14)] = acc1[d];
  }
}

// ---------------------------------------------------------------------------
// K2 fallback: strided logit reads (original validated version).
// ---------------------------------------------------------------------------
__global__ __launch_bounds__(256) void k2_softmax(
    float* __restrict__ out, const float* __restrict__ cst,
    float4* __restrict__ ws)
{
  const int tid = threadIdx.x;
  const int pl = tid & 63;
  const int t  = tid >> 6;
  const int pix = blockIdx.x * 64 + pl;
  const int b = pix >> 14, hw = pix & 16383;
  float* base = out + ATTN_OFF + ((b * 196 + t) << 14) + hw;

  float v[49];
#pragma unroll
  for (int d = 0; d < 49; ++d) v[d] = base[(d * 4) << 14];

  float mx = -1e30f;
#pragma unroll
  for (int d = 0; d < 49; ++d) mx = fmaxf(mx, v[d]);

  __shared__ float red[4][64];
  red[t][pl] = mx;
  __syncthreads();
  float M = fmaxf(fmaxf(red[0][pl], red[1][pl]), fmaxf(red[2][pl], red[3][pl]));
  M = fmaxf(M, cst[0]);
  __syncthreads();

  float s = 0.f;
#pragma unroll
  for (int d = 0; d < 49; ++d) { v[d] = __expf(v[d] - M); s += v[d]; }
  red[t][pl] = s;
  __syncthreads();
  const float l = red[0][pl] + red[1][pl] + red[2][pl] + red[3][pl]
                + __expf(cst[0] - M);
  const float inv = 1.f / l;
#pragma unroll
  for (int d = 0; d < 49; ++d) {
    const float r = v[d] * inv;
    base[(d * 4) << 14] = r;
    v[d] = r;
  }

  if (ws) {
    const int h = hw >> 7, wc = hw & 127;
    const int G    = ((h >> 1) << 2) + (wc >> 5);
    const int lane = ((h & 1) << 5) + (wc & 31);
    float4* dst = ws + (size_t)(((b * 256 + G) * 4 + t) * 13) * 64 + lane;
#pragma unroll
    for (int g = 0; g < 13; ++g) {
      float4 p;
      p.x = v[g * 4];
      p.y = (g < 12) ? v[g * 4 + 1] : 0.f;
      p.z = (g < 12) ? v[g * 4 + 2] : 0.f;
      p.w = (g < 12) ? v[g * 4 + 3] : 0.f;
      dst[g * 64] = p;
    }
  }
}

// ---------------------------------------------------------------------------
// K3 v4 (FROZEN, ~45 us): high-occupancy 1-pixel/thread structure.
// ---------------------------------------------------------------------------
__global__ __launch_bounds__(256) void k3_read_ws(
    const float* __restrict__ m_out, float* __restrict__ out,
    const float4* __restrict__ ws)
{
  const int b = blockIdx.z >> 2, cq = blockIdx.z & 3;
  const int h0 = blockIdx.y * 8, w0 = blockIdx.x * 32;
  const int tid = threadIdx.x;
  const int tx = tid & 31, ty = tid >> 5;
  const int h = h0 + ty, w = w0 + tx;
  const int waveid = tid >> 6, lane = tid & 63;
  const int G = ((h0 >> 1) + waveid) * 4 + blockIdx.x;

  __shared__ float m_s[4][14][42][4];  // 37,632 B

  float acc[16];
#pragma unroll
  for (int i = 0; i < 16; ++i) acc[i] = 0.f;

#pragma unroll 1
  for (int t = 0; t < 4; ++t) {
    const float4* ap = ws + (size_t)(((b * 256 + G) * 4 + t) * 13) * 64 + lane;

    __syncthreads();
    {
      const float* base = m_out + (((b * 64 + cq * 16) * 4 + t) << 14);
#pragma unroll
      for (int k = 0; k < 9; ++k) {
        const int item = tid + (k << 8);
        if (item < 2128) {
          const int quad = item / 532;
          const int rem  = item - 532 * quad;
          const int y  = rem / 38;
          const int xi = rem - 38 * y;
          const int gy = h0 - 3 + y, gx = w0 - 3 + xi;
          float4 v = make_float4(0.f, 0.f, 0.f, 0.f);
          if ((unsigned)gy < 128u && (unsigned)gx < 128u) {
            const float* p = base + (quad << 18) + (gy << 7) + gx;
            v.x = p[0];
            v.y = p[1 << 16];
            v.z = p[2 << 16];
            v.w = p[3 << 16];
          }
          *(float4*)&m_s[quad][y][xi + 1][0] = v;
        }
      }
    }
    __syncthreads();

    float4 cur = ap[0];
#pragma unroll
    for (int g = 0; g < 13; ++g) {
      float4 nxt = cur;
      if (g < 12) nxt = ap[(g + 1) * 64];
#pragma unroll
      for (int j = 0; j < 4; ++j) {
        const int d = g * 4 + j;
        if (d >= 49) break;
        const int dy = d / 7, dx = d % 7;
        const float av = (j == 0) ? cur.x : (j == 1) ? cur.y
                       : (j == 2) ? cur.z : cur.w;
#pragma unroll
        for (int q = 0; q < 4; ++q) {
          const float4 mv = *(const float4*)&m_s[q][ty + dy][tx + dx + 1][0];
          acc[q * 4 + 0] += av * mv.x;
          acc[q * 4 + 1] += av * mv.y;
          acc[q * 4 + 2] += av * mv.z;
          acc[q * 4 + 3] += av * mv.w;
        }
      }
      cur = nxt;
    }
  }

#pragma unroll
  for (int q = 0; q < 4; ++q)
#pragma unroll
    for (int k = 0; k < 4; ++k)
      out[((b * 64 + cq * 16 + q * 4 + k) << 14) + (h << 7) + w] = acc[q * 4 + k];
}

// ---------------------------------------------------------------------------
// K3 fallback (unchanged) — used only if ws_size is too small.
// ---------------------------------------------------------------------------
__global__ __launch_bounds__(256) void k3_read_fb(
    const float* __restrict__ m_out, float* __restrict__ out)
{
  const int b = blockIdx.z >> 2, cq = blockIdx.z & 3;
  const int h0 = blockIdx.y * 8, w0 = blockIdx.x * 32;
  const int tid = threadIdx.x;
  const int tx = tid & 31, ty = tid >> 5;
  const int h = h0 + ty, w = w0 + tx;

  __shared__ float m_s[4][14][38][4];
  const float* __restrict__ attn = out + ATTN_OFF;

  float acc[16];
#pragma unroll
  for (int i = 0; i < 16; ++i) acc[i] = 0.f;

#pragma unroll 1
  for (int t = 0; t < 4; ++t) {
    float a[49];
#pragma unroll
    for (int d = 0; d < 49; ++d)
      a[d] = attn[((b * 196 + d * 4 + t) << 14) + (h << 7) + w];

    __syncthreads();
    for (int e = tid; e < 8512; e += 256) {
      int c16 = e / 532; int rem = e - c16 * 532;
      int y = rem / 38;  int x = rem - y * 38;
      int gy = h0 - 3 + y, gx = w0 - 3 + x;
      float v = 0.f;
      if (gy >= 0 && gy < 128 && gx >= 0 && gx < 128)
        v = m_out[(((b * 64 + cq * 16 + c16) * 4 + t) << 14) + (gy << 7) + gx];
      m_s[c16 >> 2][y][x][c16 & 3] = v;
    }
    __syncthreads();

#pragma unroll
    for (int dy = 0; dy < 7; ++dy)
#pragma unroll
      for (int dx = 0; dx < 7; ++dx) {
        const float av = a[dy * 7 + dx];
#pragma unroll
        for (int q = 0; q < 4; ++q) {
          const float4 mv = *(const float4*)&m_s[q][ty + dy][tx + dx][0];
          acc[q * 4 + 0] += av * mv.x;
          acc[q * 4 + 1] += av * mv.y;
          acc[q * 4 + 2] += av * mv.z;
          acc[q * 4 + 3] += av * mv.w;
        }
      }
  }

#pragma unroll
  for (int q = 0; q < 4; ++q)
#pragma unroll
    for (int k = 0; k < 4; ++k)
      out[((b * 64 + cq * 16 + q * 4 + k) << 14) + (h << 7) + w] = acc[q * 4 + k];
}

extern "C" void kernel_launch(void* const* d_in, const int* in_sizes, int n_in,
                              void* d_out, int out_size, void* d_ws, size_t ws_size,
                              hipStream_t stream) {
  const float* m_in  = (const float*)d_in[0];
  const float* m_out = (const float*)d_in[1];
  const float* q_in  = (const float*)d_in[2];
  const float* cst   = (const float*)d_in[3];
  float* out = (float*)d_out;

  const size_t WS_BYTES = WS_F4_COUNT * 16ull;
  const bool use_split = (ws_size >= 3 * WS_BYTES) && d_ws != nullptr;
  const bool use_ws    = (ws_size >= WS_BYTES) && d_ws != nullptr;
  float4* ws = (float4*)d_ws;

  if (use_split) {
    k1_corr_split<<<dim3(4, 8, 32), dim3(256), 0, stream>>>(m_in, q_in, ws);
    k2_softmax_split<<<dim3(1024), dim3(256), 0, stream>>>(out, cst, ws);
    k3_read_ws<<<dim3(4, 16, 16), dim3(256), 0, stream>>>(m_out, out, ws);
  } else {
    k1_corr<<<dim3(4, 8, 16), dim3(256), 0, stream>>>(m_in, q_in, out);
    k2_softmax<<<dim3(1024), dim3(256), 0, stream>>>(out, cst, use_ws ? ws : nullptr);
    if (use_ws)
      k3_read_ws<<<dim3(4, 16, 16), dim3(256), 0, stream>>>(m_out, out, ws);
    else
      k3_read_fb<<<dim3(4, 16, 16), dim3(256), 0, stream>>>(m_out, out);
  }
}

// Round 7
// 168.378 us; speedup vs baseline: 5.1783x; 1.2079x over previous
//
#include <hip/hip_runtime.h>

// Problem constants: B=4, De=Do=64, T=4, H=W=128, PATCH=7, R=3
#define ATTN_OFF 4194304                 // B*Do*H*W (mem region size in floats)
// packed attn ws: [b][G=256][t][13][64] float4  = 3,407,872 float4s
#define WS_F4_COUNT 3407872ull

// ---------------------------------------------------------------------------
// K1 v7: correlation logits, small-chunk high-occupancy variant.
//  - R4-proven structure: 2 vertical px/thread (tile 32x16), 8-row shared
//    window, single LDS buffer, conflict-free immediate-write staging.
//  - chunk = 4 channels (was 8) -> LDS 14,784 B -> 4 blocks/CU co-resident
//    (R6 showed 29.7 KB pins occupancy at ~2 blocks/CU; co-residency is the
//    only latency-hiding mechanism that hasn't spilled).
//  - channel summation order unchanged -> numerics identical to R4.
// ---------------------------------------------------------------------------
__global__ __launch_bounds__(256, 2) void k1_corr(
    const float* __restrict__ m_in, const float* __restrict__ q_in,
    float* __restrict__ out)
{
  const int b = blockIdx.z >> 2, t = blockIdx.z & 3;
  const int h0 = blockIdx.y * 16, w0 = blockIdx.x * 32;
  const int tid = threadIdx.x;
  const int tx = tid & 31, ty = tid >> 5;

  // [y 0..21][x 0..41][c%4]; slot xi+1 <-> gx = w0-3+xi
  __shared__ float m_s[22][42][4];      // 14,784 B

  float acc0[49], acc1[49];
#pragma unroll
  for (int d = 0; d < 49; ++d) { acc0[d] = 0.f; acc1[d] = 0.f; }

#pragma unroll 1
  for (int cc = 0; cc < 16; ++cc) {     // 16 chunks x 4 channels
    __syncthreads();                    // prev chunk's reads complete
    {
      // 836 items = 22 rows x 38 xi ; 4-channel gather -> one b128 write
      const float* base = m_in + (((b * 64 + cc * 4) * 4 + t) << 14);
#pragma unroll
      for (int k = 0; k < 4; ++k) {
        const int item = tid + (k << 8);
        if (item < 836) {
          const int y  = item / 38;             // magic-mul
          const int xi = item - 38 * y;
          const int gy = h0 - 3 + y, gx = w0 - 3 + xi;
          float4 v = make_float4(0.f, 0.f, 0.f, 0.f);
          if ((unsigned)gy < 128u && (unsigned)gx < 128u) {
            const float* p = base + (gy << 7) + gx;
            v.x = p[0];
            v.y = p[1 << 16];
            v.z = p[2 << 16];
            v.w = p[3 << 16];
          }
          *(float4*)&m_s[y][xi + 1][0] = v;
        }
      }
    }
    __syncthreads();

    float q0[4], q1[4];
#pragma unroll
    for (int k = 0; k < 4; ++k) {
      const float* qp = q_in + ((b * 64 + cc * 4 + k) << 14)
                      + ((h0 + 2 * ty) << 7) + w0 + tx;
      q0[k] = qp[0];
      q1[k] = qp[128];
    }
#pragma unroll
    for (int wr = 0; wr < 8; ++wr) {    // shared 8-row window, 2 pixels
      const float4* rowp = (const float4*)&m_s[2 * ty + wr][tx + 1][0];
#pragma unroll
      for (int dx = 0; dx < 7; ++dx) {
        const float4 mv = rowp[dx];
        if (wr < 7)
          acc0[wr * 7 + dx] += q0[0]*mv.x + q0[1]*mv.y + q0[2]*mv.z + q0[3]*mv.w;
        if (wr > 0)
          acc1[(wr - 1) * 7 + dx] += q1[0]*mv.x + q1[1]*mv.y + q1[2]*mv.z + q1[3]*mv.w;
      }
    }
  }

  const int obase = ATTN_OFF + ((b * 196 + t) << 14)
                  + ((h0 + 2 * ty) << 7) + w0 + tx;
#pragma unroll
  for (int d = 0; d < 49; ++d) {
    out[obase +       ((d * 4) << 14)] = acc0[d];
    out[obase + 128 + ((d * 4) << 14)] = acc1[d];
  }
}

// ---------------------------------------------------------------------------
// K2 (validated, ~31 us): softmax + packed-attn write into d_ws.
// Packed layout keyed to k3's wave tiling: G = (h>>1)*4 + (w>>5),
// lane = (h&1)*32 + (w&31); element (b,G,t,g,lane) at
// ((b*256+G)*4+t)*13*64 + g*64 + lane   (float4 units, d = 4g+j).
// ---------------------------------------------------------------------------
__global__ __launch_bounds__(256) void k2_softmax(
    float* __restrict__ out, const float* __restrict__ cst,
    float4* __restrict__ ws)
{
  const int tid = threadIdx.x;
  const int pl = tid & 63;             // pixel within block
  const int t  = tid >> 6;
  const int pix = blockIdx.x * 64 + pl;      // 65536 pixels total
  const int b = pix >> 14, hw = pix & 16383;
  float* base = out + ATTN_OFF + ((b * 196 + t) << 14) + hw;

  float v[49];
#pragma unroll
  for (int d = 0; d < 49; ++d) v[d] = base[(d * 4) << 14];

  float mx = -1e30f;
#pragma unroll
  for (int d = 0; d < 49; ++d) mx = fmaxf(mx, v[d]);

  __shared__ float red[4][64];
  red[t][pl] = mx;
  __syncthreads();
  float M = fmaxf(fmaxf(red[0][pl], red[1][pl]), fmaxf(red[2][pl], red[3][pl]));
  M = fmaxf(M, cst[0]);
  __syncthreads();

  float s = 0.f;
#pragma unroll
  for (int d = 0; d < 49; ++d) { v[d] = __expf(v[d] - M); s += v[d]; }
  red[t][pl] = s;
  __syncthreads();
  const float l = red[0][pl] + red[1][pl] + red[2][pl] + red[3][pl]
                + __expf(cst[0] - M);
  const float inv = 1.f / l;
#pragma unroll
  for (int d = 0; d < 49; ++d) {
    const float r = v[d] * inv;
    base[(d * 4) << 14] = r;           // reference-layout output (validated)
    v[d] = r;
  }

  if (ws) {
    const int h = hw >> 7, wc = hw & 127;
    const int G    = ((h >> 1) << 2) + (wc >> 5);
    const int lane = ((h & 1) << 5) + (wc & 31);
    float4* dst = ws + (size_t)(((b * 256 + G) * 4 + t) * 13) * 64 + lane;
#pragma unroll
    for (int g = 0; g < 13; ++g) {
      float4 p;
      p.x = v[g * 4];
      p.y = (g < 12) ? v[g * 4 + 1] : 0.f;
      p.z = (g < 12) ? v[g * 4 + 2] : 0.f;
      p.w = (g < 12) ? v[g * 4 + 3] : 0.f;
      dst[g * 64] = p;
    }
  }
}

// ---------------------------------------------------------------------------
// K3 v4 (FROZEN, ~45 us ~= its 42 us LDS-pipe floor): high-occupancy
// 1-pixel/thread structure, conflict-free staging, g-pipelined ws reads.
// ---------------------------------------------------------------------------
__global__ __launch_bounds__(256) void k3_read_ws(
    const float* __restrict__ m_out, float* __restrict__ out,
    const float4* __restrict__ ws)
{
  const int b = blockIdx.z >> 2, cq = blockIdx.z & 3;
  const int h0 = blockIdx.y * 8, w0 = blockIdx.x * 32;
  const int tid = threadIdx.x;
  const int tx = tid & 31, ty = tid >> 5;
  const int h = h0 + ty, w = w0 + tx;
  const int waveid = tid >> 6, lane = tid & 63;
  const int G = ((h0 >> 1) + waveid) * 4 + blockIdx.x;

  __shared__ float m_s[4][14][42][4];  // 37,632 B

  float acc[16];
#pragma unroll
  for (int i = 0; i < 16; ++i) acc[i] = 0.f;

#pragma unroll 1
  for (int t = 0; t < 4; ++t) {
    const float4* ap = ws + (size_t)(((b * 256 + G) * 4 + t) * 13) * 64 + lane;

    __syncthreads();
    {
      const float* base = m_out + (((b * 64 + cq * 16) * 4 + t) << 14);
#pragma unroll
      for (int k = 0; k < 9; ++k) {
        const int item = tid + (k << 8);
        if (item < 2128) {
          const int quad = item / 532;
          const int rem  = item - 532 * quad;
          const int y  = rem / 38;
          const int xi = rem - 38 * y;
          const int gy = h0 - 3 + y, gx = w0 - 3 + xi;
          float4 v = make_float4(0.f, 0.f, 0.f, 0.f);
          if ((unsigned)gy < 128u && (unsigned)gx < 128u) {
            const float* p = base + (quad << 18) + (gy << 7) + gx;
            v.x = p[0];
            v.y = p[1 << 16];
            v.z = p[2 << 16];
            v.w = p[3 << 16];
          }
          *(float4*)&m_s[quad][y][xi + 1][0] = v;
        }
      }
    }
    __syncthreads();

    float4 cur = ap[0];
#pragma unroll
    for (int g = 0; g < 13; ++g) {
      float4 nxt = cur;
      if (g < 12) nxt = ap[(g + 1) * 64];
#pragma unroll
      for (int j = 0; j < 4; ++j) {
        const int d = g * 4 + j;
        if (d >= 49) break;
        const int dy = d / 7, dx = d % 7;
        const float av = (j == 0) ? cur.x : (j == 1) ? cur.y
                       : (j == 2) ? cur.z : cur.w;
#pragma unroll
        for (int q = 0; q < 4; ++q) {
          const float4 mv = *(const float4*)&m_s[q][ty + dy][tx + dx + 1][0];
          acc[q * 4 + 0] += av * mv.x;
          acc[q * 4 + 1] += av * mv.y;
          acc[q * 4 + 2] += av * mv.z;
          acc[q * 4 + 3] += av * mv.w;
        }
      }
      cur = nxt;
    }
  }

#pragma unroll
  for (int q = 0; q < 4; ++q)
#pragma unroll
    for (int k = 0; k < 4; ++k)
      out[((b * 64 + cq * 16 + q * 4 + k) << 14) + (h << 7) + w] = acc[q * 4 + k];
}

// ---------------------------------------------------------------------------
// K3 fallback (unchanged) — used only if ws_size is too small.
// ---------------------------------------------------------------------------
__global__ __launch_bounds__(256) void k3_read_fb(
    const float* __restrict__ m_out, float* __restrict__ out)
{
  const int b = blockIdx.z >> 2, cq = blockIdx.z & 3;
  const int h0 = blockIdx.y * 8, w0 = blockIdx.x * 32;
  const int tid = threadIdx.x;
  const int tx = tid & 31, ty = tid >> 5;
  const int h = h0 + ty, w = w0 + tx;

  __shared__ float m_s[4][14][38][4];
  const float* __restrict__ attn = out + ATTN_OFF;

  float acc[16];
#pragma unroll
  for (int i = 0; i < 16; ++i) acc[i] = 0.f;

#pragma unroll 1
  for (int t = 0; t < 4; ++t) {
    float a[49];
#pragma unroll
    for (int d = 0; d < 49; ++d)
      a[d] = attn[((b * 196 + d * 4 + t) << 14) + (h << 7) + w];

    __syncthreads();
    for (int e = tid; e < 8512; e += 256) {
      int c16 = e / 532; int rem = e - c16 * 532;
      int y = rem / 38;  int x = rem - y * 38;
      int gy = h0 - 3 + y, gx = w0 - 3 + x;
      float v = 0.f;
      if (gy >= 0 && gy < 128 && gx >= 0 && gx < 128)
        v = m_out[(((b * 64 + cq * 16 + c16) * 4 + t) << 14) + (gy << 7) + gx];
      m_s[c16 >> 2][y][x][c16 & 3] = v;
    }
    __syncthreads();

#pragma unroll
    for (int dy = 0; dy < 7; ++dy)
#pragma unroll
      for (int dx = 0; dx < 7; ++dx) {
        const float av = a[dy * 7 + dx];
#pragma unroll
        for (int q = 0; q < 4; ++q) {
          const float4 mv = *(const float4*)&m_s[q][ty + dy][tx + dx][0];
          acc[q * 4 + 0] += av * mv.x;
          acc[q * 4 + 1] += av * mv.y;
          acc[q * 4 + 2] += av * mv.z;
          acc[q * 4 + 3] += av * mv.w;
        }
      }
  }

#pragma unroll
  for (int q = 0; q < 4; ++q)
#pragma unroll
    for (int k = 0; k < 4; ++k)
      out[((b * 64 + cq * 16 + q * 4 + k) << 14) + (h << 7) + w] = acc[q * 4 + k];
}

extern "C" void kernel_launch(void* const* d_in, const int* in_sizes, int n_in,
                              void* d_out, int out_size, void* d_ws, size_t ws_size,
                              hipStream_t stream) {
  const float* m_in  = (const float*)d_in[0];
  const float* m_out = (const float*)d_in[1];
  const float* q_in  = (const float*)d_in[2];
  const float* cst   = (const float*)d_in[3];
  float* out = (float*)d_out;

  const bool use_ws = (ws_size >= WS_F4_COUNT * 16ull) && d_ws != nullptr;
  float4* ws = use_ws ? (float4*)d_ws : nullptr;

  k1_corr<<<dim3(4, 8, 16), dim3(256), 0, stream>>>(m_in, q_in, out);
  k2_softmax<<<dim3(1024), dim3(256), 0, stream>>>(out, cst, ws);
  if (use_ws)
    k3_read_ws<<<dim3(4, 16, 16), dim3(256), 0, stream>>>(m_out, out, ws);
  else
    k3_read_fb<<<dim3(4, 16, 16), dim3(256), 0, stream>>>(m_out, out);
}

// Round 8
// 159.367 us; speedup vs baseline: 5.4711x; 1.0565x over previous
//
#include <hip/hip_runtime.h>

// Problem constants: B=4, De=Do=64, T=4, H=W=128, PATCH=7, R=3
#define ATTN_OFF 4194304                 // B*Do*H*W (mem region size in floats)
// packed attn ws: [b][G=256][t][13][64] float4  = 3,407,872 float4s
#define WS_F4_COUNT 3407872ull

// ---------------------------------------------------------------------------
// K1 v8: correlation logits, k3-clone structure (k3 is proven to run at its
// LDS-pipe floor with this exact shape).
//  - tile 32x8, 1 px/thread, 4-channel chunks, LDS [14][42][4] = 9,408 B,
//    grid (4,16,16) = 1024 blocks = 4 blocks/CU = 16 waves/CU.
//    (R7 proved k1 was GRID-limited at 2 blocks/CU: LDS 14.8 KB + VGPR 80
//    but occupancy stuck at 19% with 512 blocks.)
//  - conflict-free staging: per-item 4-channel gather -> one ds_write_b128.
//  - channel order ascending, 4 at a time -> numerics identical.
// ---------------------------------------------------------------------------
__global__ __launch_bounds__(256) void k1_corr(
    const float* __restrict__ m_in, const float* __restrict__ q_in,
    float* __restrict__ out)
{
  const int b = blockIdx.z >> 2, t = blockIdx.z & 3;
  const int h0 = blockIdx.y * 8, w0 = blockIdx.x * 32;
  const int tid = threadIdx.x;
  const int tx = tid & 31, ty = tid >> 5;
  const int h = h0 + ty, w = w0 + tx;

  // [y 0..13][x 0..41][c%4]; slot xi+1 <-> gx = w0-3+xi
  __shared__ float m_s[14][42][4];      // 9,408 B

  float acc[49];
#pragma unroll
  for (int d = 0; d < 49; ++d) acc[d] = 0.f;

#pragma unroll 1
  for (int cc = 0; cc < 16; ++cc) {     // 16 chunks x 4 channels
    __syncthreads();                    // prev chunk's reads complete
    {
      // 532 items = 14 rows x 38 xi ; 4-channel gather -> one b128 write
      const float* base = m_in + (((b * 64 + cc * 4) * 4 + t) << 14);
#pragma unroll
      for (int k = 0; k < 3; ++k) {
        const int item = tid + (k << 8);
        if (item < 532) {
          const int y  = item / 38;             // magic-mul
          const int xi = item - 38 * y;
          const int gy = h0 - 3 + y, gx = w0 - 3 + xi;
          float4 v = make_float4(0.f, 0.f, 0.f, 0.f);
          if ((unsigned)gy < 128u && (unsigned)gx < 128u) {
            const float* p = base + (gy << 7) + gx;
            v.x = p[0];
            v.y = p[1 << 16];
            v.z = p[2 << 16];
            v.w = p[3 << 16];
          }
          *(float4*)&m_s[y][xi + 1][0] = v;
        }
      }
    }
    __syncthreads();

    float q0[4];
#pragma unroll
    for (int k = 0; k < 4; ++k)
      q0[k] = q_in[((b * 64 + cc * 4 + k) << 14) + (h << 7) + w];
#pragma unroll
    for (int dy = 0; dy < 7; ++dy)
#pragma unroll
      for (int dx = 0; dx < 7; ++dx) {
        const float4 mv = *(const float4*)&m_s[ty + dy][tx + 1 + dx][0];
        acc[dy * 7 + dx] += q0[0]*mv.x + q0[1]*mv.y + q0[2]*mv.z + q0[3]*mv.w;
      }
  }

  const int obase = ATTN_OFF + ((b * 196 + t) << 14) + (h << 7) + w;
#pragma unroll
  for (int d = 0; d < 49; ++d)
    out[obase + ((d * 4) << 14)] = acc[d];
}

// ---------------------------------------------------------------------------
// K2 (validated, ~31 us): softmax + packed-attn write into d_ws.
// Packed layout keyed to k3's wave tiling: G = (h>>1)*4 + (w>>5),
// lane = (h&1)*32 + (w&31); element (b,G,t,g,lane) at
// ((b*256+G)*4+t)*13*64 + g*64 + lane   (float4 units, d = 4g+j).
// ---------------------------------------------------------------------------
__global__ __launch_bounds__(256) void k2_softmax(
    float* __restrict__ out, const float* __restrict__ cst,
    float4* __restrict__ ws)
{
  const int tid = threadIdx.x;
  const int pl = tid & 63;             // pixel within block
  const int t  = tid >> 6;
  const int pix = blockIdx.x * 64 + pl;      // 65536 pixels total
  const int b = pix >> 14, hw = pix & 16383;
  float* base = out + ATTN_OFF + ((b * 196 + t) << 14) + hw;

  float v[49];
#pragma unroll
  for (int d = 0; d < 49; ++d) v[d] = base[(d * 4) << 14];

  float mx = -1e30f;
#pragma unroll
  for (int d = 0; d < 49; ++d) mx = fmaxf(mx, v[d]);

  __shared__ float red[4][64];
  red[t][pl] = mx;
  __syncthreads();
  float M = fmaxf(fmaxf(red[0][pl], red[1][pl]), fmaxf(red[2][pl], red[3][pl]));
  M = fmaxf(M, cst[0]);
  __syncthreads();

  float s = 0.f;
#pragma unroll
  for (int d = 0; d < 49; ++d) { v[d] = __expf(v[d] - M); s += v[d]; }
  red[t][pl] = s;
  __syncthreads();
  const float l = red[0][pl] + red[1][pl] + red[2][pl] + red[3][pl]
                + __expf(cst[0] - M);
  const float inv = 1.f / l;
#pragma unroll
  for (int d = 0; d < 49; ++d) {
    const float r = v[d] * inv;
    base[(d * 4) << 14] = r;           // reference-layout output (validated)
    v[d] = r;
  }

  if (ws) {
    const int h = hw >> 7, wc = hw & 127;
    const int G    = ((h >> 1) << 2) + (wc >> 5);
    const int lane = ((h & 1) << 5) + (wc & 31);
    float4* dst = ws + (size_t)(((b * 256 + G) * 4 + t) * 13) * 64 + lane;
#pragma unroll
    for (int g = 0; g < 13; ++g) {
      float4 p;
      p.x = v[g * 4];
      p.y = (g < 12) ? v[g * 4 + 1] : 0.f;
      p.z = (g < 12) ? v[g * 4 + 2] : 0.f;
      p.w = (g < 12) ? v[g * 4 + 3] : 0.f;
      dst[g * 64] = p;
    }
  }
}

// ---------------------------------------------------------------------------
// K3 v4 (FROZEN, ~45 us ~= its LDS-pipe floor): high-occupancy
// 1-pixel/thread structure, conflict-free staging, g-pipelined ws reads.
// ---------------------------------------------------------------------------
__global__ __launch_bounds__(256) void k3_read_ws(
    const float* __restrict__ m_out, float* __restrict__ out,
    const float4* __restrict__ ws)
{
  const int b = blockIdx.z >> 2, cq = blockIdx.z & 3;
  const int h0 = blockIdx.y * 8, w0 = blockIdx.x * 32;
  const int tid = threadIdx.x;
  const int tx = tid & 31, ty = tid >> 5;
  const int h = h0 + ty, w = w0 + tx;
  const int waveid = tid >> 6, lane = tid & 63;
  const int G = ((h0 >> 1) + waveid) * 4 + blockIdx.x;

  __shared__ float m_s[4][14][42][4];  // 37,632 B

  float acc[16];
#pragma unroll
  for (int i = 0; i < 16; ++i) acc[i] = 0.f;

#pragma unroll 1
  for (int t = 0; t < 4; ++t) {
    const float4* ap = ws + (size_t)(((b * 256 + G) * 4 + t) * 13) * 64 + lane;

    __syncthreads();
    {
      const float* base = m_out + (((b * 64 + cq * 16) * 4 + t) << 14);
#pragma unroll
      for (int k = 0; k < 9; ++k) {
        const int item = tid + (k << 8);
        if (item < 2128) {
          const int quad = item / 532;
          const int rem  = item - 532 * quad;
          const int y  = rem / 38;
          const int xi = rem - 38 * y;
          const int gy = h0 - 3 + y, gx = w0 - 3 + xi;
          float4 v = make_float4(0.f, 0.f, 0.f, 0.f);
          if ((unsigned)gy < 128u && (unsigned)gx < 128u) {
            const float* p = base + (quad << 18) + (gy << 7) + gx;
            v.x = p[0];
            v.y = p[1 << 16];
            v.z = p[2 << 16];
            v.w = p[3 << 16];
          }
          *(float4*)&m_s[quad][y][xi + 1][0] = v;
        }
      }
    }
    __syncthreads();

    float4 cur = ap[0];
#pragma unroll
    for (int g = 0; g < 13; ++g) {
      float4 nxt = cur;
      if (g < 12) nxt = ap[(g + 1) * 64];
#pragma unroll
      for (int j = 0; j < 4; ++j) {
        const int d = g * 4 + j;
        if (d >= 49) break;
        const int dy = d / 7, dx = d % 7;
        const float av = (j == 0) ? cur.x : (j == 1) ? cur.y
                       : (j == 2) ? cur.z : cur.w;
#pragma unroll
        for (int q = 0; q < 4; ++q) {
          const float4 mv = *(const float4*)&m_s[q][ty + dy][tx + dx + 1][0];
          acc[q * 4 + 0] += av * mv.x;
          acc[q * 4 + 1] += av * mv.y;
          acc[q * 4 + 2] += av * mv.z;
          acc[q * 4 + 3] += av * mv.w;
        }
      }
      cur = nxt;
    }
  }

#pragma unroll
  for (int q = 0; q < 4; ++q)
#pragma unroll
    for (int k = 0; k < 4; ++k)
      out[((b * 64 + cq * 16 + q * 4 + k) << 14) + (h << 7) + w] = acc[q * 4 + k];
}

// ---------------------------------------------------------------------------
// K3 fallback (unchanged) — used only if ws_size is too small.
// ---------------------------------------------------------------------------
__global__ __launch_bounds__(256) void k3_read_fb(
    const float* __restrict__ m_out, float* __restrict__ out)
{
  const int b = blockIdx.z >> 2, cq = blockIdx.z & 3;
  const int h0 = blockIdx.y * 8, w0 = blockIdx.x * 32;
  const int tid = threadIdx.x;
  const int tx = tid & 31, ty = tid >> 5;
  const int h = h0 + ty, w = w0 + tx;

  __shared__ float m_s[4][14][38][4];
  const float* __restrict__ attn = out + ATTN_OFF;

  float acc[16];
#pragma unroll
  for (int i = 0; i < 16; ++i) acc[i] = 0.f;

#pragma unroll 1
  for (int t = 0; t < 4; ++t) {
    float a[49];
#pragma unroll
    for (int d = 0; d < 49; ++d)
      a[d] = attn[((b * 196 + d * 4 + t) << 14) + (h << 7) + w];

    __syncthreads();
    for (int e = tid; e < 8512; e += 256) {
      int c16 = e / 532; int rem = e - c16 * 532;
      int y = rem / 38;  int x = rem - y * 38;
      int gy = h0 - 3 + y, gx = w0 - 3 + x;
      float v = 0.f;
      if (gy >= 0 && gy < 128 && gx >= 0 && gx < 128)
        v = m_out[(((b * 64 + cq * 16 + c16) * 4 + t) << 14) + (gy << 7) + gx];
      m_s[c16 >> 2][y][x][c16 & 3] = v;
    }
    __syncthreads();

#pragma unroll
    for (int dy = 0; dy < 7; ++dy)
#pragma unroll
      for (int dx = 0; dx < 7; ++dx) {
        const float av = a[dy * 7 + dx];
#pragma unroll
        for (int q = 0; q < 4; ++q) {
          const float4 mv = *(const float4*)&m_s[q][ty + dy][tx + dx][0];
          acc[q * 4 + 0] += av * mv.x;
          acc[q * 4 + 1] += av * mv.y;
          acc[q * 4 + 2] += av * mv.z;
          acc[q * 4 + 3] += av * mv.w;
        }
      }
  }

#pragma unroll
  for (int q = 0; q < 4; ++q)
#pragma unroll
    for (int k = 0; k < 4; ++k)
      out[((b * 64 + cq * 16 + q * 4 + k) << 14) + (h << 7) + w] = acc[q * 4 + k];
}

extern "C" void kernel_launch(void* const* d_in, const int* in_sizes, int n_in,
                              void* d_out, int out_size, void* d_ws, size_t ws_size,
                              hipStream_t stream) {
  const float* m_in  = (const float*)d_in[0];
  const float* m_out = (const float*)d_in[1];
  const float* q_in  = (const float*)d_in[2];
  const float* cst   = (const float*)d_in[3];
  float* out = (float*)d_out;

  const bool use_ws = (ws_size >= WS_F4_COUNT * 16ull) && d_ws != nullptr;
  float4* ws = use_ws ? (float4*)d_ws : nullptr;

  k1_corr<<<dim3(4, 16, 16), dim3(256), 0, stream>>>(m_in, q_in, out);
  k2_softmax<<<dim3(1024), dim3(256), 0, stream>>>(out, cst, ws);
  if (use_ws)
    k3_read_ws<<<dim3(4, 16, 16), dim3(256), 0, stream>>>(m_out, out, ws);
  else
    k3_read_fb<<<dim3(4, 16, 16), dim3(256), 0, stream>>>(m_out, out);
}

// Round 9
// 151.325 us; speedup vs baseline: 5.7619x; 1.0531x over previous
//
#include <hip/hip_runtime.h>

// Problem constants: B=4, De=Do=64, T=4, H=W=128, PATCH=7, R=3
#define ATTN_OFF 4194304                 // B*Do*H*W (mem region size in floats)
// packed attn ws: [b][G=256][t][13][64] float4  = 3,407,872 float4s
#define WS_F4_COUNT 3407872ull

// ---------------------------------------------------------------------------
// K1 v8 (FROZEN, ~41 us): correlation logits, k3-clone structure.
//  - tile 32x8, 1 px/thread, 4-channel chunks, LDS 9,408 B,
//    grid (4,16,16) = 1024 blocks -> true 4 blocks/CU (LDS well under pool).
//  - conflict-free staging: per-item 4-channel gather -> one ds_write_b128.
// ---------------------------------------------------------------------------
__global__ __launch_bounds__(256) void k1_corr(
    const float* __restrict__ m_in, const float* __restrict__ q_in,
    float* __restrict__ out)
{
  const int b = blockIdx.z >> 2, t = blockIdx.z & 3;
  const int h0 = blockIdx.y * 8, w0 = blockIdx.x * 32;
  const int tid = threadIdx.x;
  const int tx = tid & 31, ty = tid >> 5;
  const int h = h0 + ty, w = w0 + tx;

  // [y 0..13][x 0..41][c%4]; slot xi+1 <-> gx = w0-3+xi
  __shared__ float m_s[14][42][4];      // 9,408 B

  float acc[49];
#pragma unroll
  for (int d = 0; d < 49; ++d) acc[d] = 0.f;

#pragma unroll 1
  for (int cc = 0; cc < 16; ++cc) {     // 16 chunks x 4 channels
    __syncthreads();                    // prev chunk's reads complete
    {
      // 532 items = 14 rows x 38 xi ; 4-channel gather -> one b128 write
      const float* base = m_in + (((b * 64 + cc * 4) * 4 + t) << 14);
#pragma unroll
      for (int k = 0; k < 3; ++k) {
        const int item = tid + (k << 8);
        if (item < 532) {
          const int y  = item / 38;             // magic-mul
          const int xi = item - 38 * y;
          const int gy = h0 - 3 + y, gx = w0 - 3 + xi;
          float4 v = make_float4(0.f, 0.f, 0.f, 0.f);
          if ((unsigned)gy < 128u && (unsigned)gx < 128u) {
            const float* p = base + (gy << 7) + gx;
            v.x = p[0];
            v.y = p[1 << 16];
            v.z = p[2 << 16];
            v.w = p[3 << 16];
          }
          *(float4*)&m_s[y][xi + 1][0] = v;
        }
      }
    }
    __syncthreads();

    float q0[4];
#pragma unroll
    for (int k = 0; k < 4; ++k)
      q0[k] = q_in[((b * 64 + cc * 4 + k) << 14) + (h << 7) + w];
#pragma unroll
    for (int dy = 0; dy < 7; ++dy)
#pragma unroll
      for (int dx = 0; dx < 7; ++dx) {
        const float4 mv = *(const float4*)&m_s[ty + dy][tx + 1 + dx][0];
        acc[dy * 7 + dx] += q0[0]*mv.x + q0[1]*mv.y + q0[2]*mv.z + q0[3]*mv.w;
      }
  }

  const int obase = ATTN_OFF + ((b * 196 + t) << 14) + (h << 7) + w;
#pragma unroll
  for (int d = 0; d < 49; ++d)
    out[obase + ((d * 4) << 14)] = acc[d];
}

// ---------------------------------------------------------------------------
// K2 (FROZEN, ~31 us): softmax + packed-attn write into d_ws.
// Packed layout keyed to k3's wave tiling: G = (h>>1)*4 + (w>>5),
// lane = (h&1)*32 + (w&31); element (b,G,t,g,lane) at
// ((b*256+G)*4+t)*13*64 + g*64 + lane   (float4 units, d = 4g+j).
// ---------------------------------------------------------------------------
__global__ __launch_bounds__(256) void k2_softmax(
    float* __restrict__ out, const float* __restrict__ cst,
    float4* __restrict__ ws)
{
  const int tid = threadIdx.x;
  const int pl = tid & 63;             // pixel within block
  const int t  = tid >> 6;
  const int pix = blockIdx.x * 64 + pl;      // 65536 pixels total
  const int b = pix >> 14, hw = pix & 16383;
  float* base = out + ATTN_OFF + ((b * 196 + t) << 14) + hw;

  float v[49];
#pragma unroll
  for (int d = 0; d < 49; ++d) v[d] = base[(d * 4) << 14];

  float mx = -1e30f;
#pragma unroll
  for (int d = 0; d < 49; ++d) mx = fmaxf(mx, v[d]);

  __shared__ float red[4][64];
  red[t][pl] = mx;
  __syncthreads();
  float M = fmaxf(fmaxf(red[0][pl], red[1][pl]), fmaxf(red[2][pl], red[3][pl]));
  M = fmaxf(M, cst[0]);
  __syncthreads();

  float s = 0.f;
#pragma unroll
  for (int d = 0; d < 49; ++d) { v[d] = __expf(v[d] - M); s += v[d]; }
  red[t][pl] = s;
  __syncthreads();
  const float l = red[0][pl] + red[1][pl] + red[2][pl] + red[3][pl]
                + __expf(cst[0] - M);
  const float inv = 1.f / l;
#pragma unroll
  for (int d = 0; d < 49; ++d) {
    const float r = v[d] * inv;
    base[(d * 4) << 14] = r;           // reference-layout output (validated)
    v[d] = r;
  }

  if (ws) {
    const int h = hw >> 7, wc = hw & 127;
    const int G    = ((h >> 1) << 2) + (wc >> 5);
    const int lane = ((h & 1) << 5) + (wc & 31);
    float4* dst = ws + (size_t)(((b * 256 + G) * 4 + t) * 13) * 64 + lane;
#pragma unroll
    for (int g = 0; g < 13; ++g) {
      float4 p;
      p.x = v[g * 4];
      p.y = (g < 12) ? v[g * 4 + 1] : 0.f;
      p.z = (g < 12) ? v[g * 4 + 2] : 0.f;
      p.w = (g < 12) ? v[g * 4 + 3] : 0.f;
      dst[g * 64] = p;
    }
  }
}

// ---------------------------------------------------------------------------
// K3 v5 (packed-ws): 8-channel blocks for real 4 blocks/CU occupancy.
//  - R8 counters showed the effective LDS occupancy pool is ~80 KB: the old
//    37.6 KB tile capped k3 at 2 blocks/CU (Occupancy 23%), leaving the
//    staging latency exposed (89 us vs 42 us LDS floor).
//  - now: 2 quads (8 ch) per block, LDS [2][14][42][4] = 18,816 B,
//    grid (4,16,32) = 2048 blocks = 8/CU available, ~4 resident.
//  - total LDS-pipe work unchanged; per-block serial chain halved; numerics
//    bit-identical (channel partition; per-channel order unchanged).
// ---------------------------------------------------------------------------
__global__ __launch_bounds__(256) void k3_read_ws(
    const float* __restrict__ m_out, float* __restrict__ out,
    const float4* __restrict__ ws)
{
  const int b = blockIdx.z >> 3, cq = blockIdx.z & 7;   // 8 ch per group
  const int h0 = blockIdx.y * 8, w0 = blockIdx.x * 32;
  const int tid = threadIdx.x;
  const int tx = tid & 31, ty = tid >> 5;
  const int h = h0 + ty, w = w0 + tx;
  const int waveid = tid >> 6, lane = tid & 63;
  const int G = ((h0 >> 1) + waveid) * 4 + blockIdx.x;

  __shared__ float m_s[2][14][42][4];  // 18,816 B

  float acc[8];
#pragma unroll
  for (int i = 0; i < 8; ++i) acc[i] = 0.f;

#pragma unroll 1
  for (int t = 0; t < 4; ++t) {
    const float4* ap = ws + (size_t)(((b * 256 + G) * 4 + t) * 13) * 64 + lane;

    __syncthreads();                   // prev iter's reads complete
    {
      // 1064 items = 2 quads x 14 rows x 38 xi ; gather -> one b128 write
      const float* base = m_out + (((b * 64 + cq * 8) * 4 + t) << 14);
#pragma unroll
      for (int k = 0; k < 5; ++k) {
        const int item = tid + (k << 8);
        if (item < 1064) {
          const int quad = item >= 532;
          const int rem  = item - 532 * quad;
          const int y  = rem / 38;
          const int xi = rem - 38 * y;
          const int gy = h0 - 3 + y, gx = w0 - 3 + xi;
          float4 v = make_float4(0.f, 0.f, 0.f, 0.f);
          if ((unsigned)gy < 128u && (unsigned)gx < 128u) {
            const float* p = base + (quad << 18) + (gy << 7) + gx;
            v.x = p[0];
            v.y = p[1 << 16];
            v.z = p[2 << 16];
            v.w = p[3 << 16];
          }
          *(float4*)&m_s[quad][y][xi + 1][0] = v;
        }
      }
    }
    __syncthreads();

    float4 cur = ap[0];
#pragma unroll
    for (int g = 0; g < 13; ++g) {
      float4 nxt = cur;
      if (g < 12) nxt = ap[(g + 1) * 64];
#pragma unroll
      for (int j = 0; j < 4; ++j) {
        const int d = g * 4 + j;
        if (d >= 49) break;
        const int dy = d / 7, dx = d % 7;
        const float av = (j == 0) ? cur.x : (j == 1) ? cur.y
                       : (j == 2) ? cur.z : cur.w;
#pragma unroll
        for (int q = 0; q < 2; ++q) {
          const float4 mv = *(const float4*)&m_s[q][ty + dy][tx + dx + 1][0];
          acc[q * 4 + 0] += av * mv.x;
          acc[q * 4 + 1] += av * mv.y;
          acc[q * 4 + 2] += av * mv.z;
          acc[q * 4 + 3] += av * mv.w;
        }
      }
      cur = nxt;
    }
  }

#pragma unroll
  for (int q = 0; q < 2; ++q)
#pragma unroll
    for (int k = 0; k < 4; ++k)
      out[((b * 64 + cq * 8 + q * 4 + k) << 14) + (h << 7) + w] = acc[q * 4 + k];
}

// ---------------------------------------------------------------------------
// K3 fallback (unchanged) — used only if ws_size is too small.
// ---------------------------------------------------------------------------
__global__ __launch_bounds__(256) void k3_read_fb(
    const float* __restrict__ m_out, float* __restrict__ out)
{
  const int b = blockIdx.z >> 2, cq = blockIdx.z & 3;
  const int h0 = blockIdx.y * 8, w0 = blockIdx.x * 32;
  const int tid = threadIdx.x;
  const int tx = tid & 31, ty = tid >> 5;
  const int h = h0 + ty, w = w0 + tx;

  __shared__ float m_s[4][14][38][4];
  const float* __restrict__ attn = out + ATTN_OFF;

  float acc[16];
#pragma unroll
  for (int i = 0; i < 16; ++i) acc[i] = 0.f;

#pragma unroll 1
  for (int t = 0; t < 4; ++t) {
    float a[49];
#pragma unroll
    for (int d = 0; d < 49; ++d)
      a[d] = attn[((b * 196 + d * 4 + t) << 14) + (h << 7) + w];

    __syncthreads();
    for (int e = tid; e < 8512; e += 256) {
      int c16 = e / 532; int rem = e - c16 * 532;
      int y = rem / 38;  int x = rem - y * 38;
      int gy = h0 - 3 + y, gx = w0 - 3 + x;
      float v = 0.f;
      if (gy >= 0 && gy < 128 && gx >= 0 && gx < 128)
        v = m_out[(((b * 64 + cq * 16 + c16) * 4 + t) << 14) + (gy << 7) + gx];
      m_s[c16 >> 2][y][x][c16 & 3] = v;
    }
    __syncthreads();

#pragma unroll
    for (int dy = 0; dy < 7; ++dy)
#pragma unroll
      for (int dx = 0; dx < 7; ++dx) {
        const float av = a[dy * 7 + dx];
#pragma unroll
        for (int q = 0; q < 4; ++q) {
          const float4 mv = *(const float4*)&m_s[q][ty + dy][tx + dx][0];
          acc[q * 4 + 0] += av * mv.x;
          acc[q * 4 + 1] += av * mv.y;
          acc[q * 4 + 2] += av * mv.z;
          acc[q * 4 + 3] += av * mv.w;
        }
      }
  }

#pragma unroll
  for (int q = 0; q < 4; ++q)
#pragma unroll
    for (int k = 0; k < 4; ++k)
      out[((b * 64 + cq * 16 + q * 4 + k) << 14) + (h << 7) + w] = acc[q * 4 + k];
}

extern "C" void kernel_launch(void* const* d_in, const int* in_sizes, int n_in,
                              void* d_out, int out_size, void* d_ws, size_t ws_size,
                              hipStream_t stream) {
  const float* m_in  = (const float*)d_in[0];
  const float* m_out = (const float*)d_in[1];
  const float* q_in  = (const float*)d_in[2];
  const float* cst   = (const float*)d_in[3];
  float* out = (float*)d_out;

  const bool use_ws = (ws_size >= WS_F4_COUNT * 16ull) && d_ws != nullptr;
  float4* ws = use_ws ? (float4*)d_ws : nullptr;

  k1_corr<<<dim3(4, 16, 16), dim3(256), 0, stream>>>(m_in, q_in, out);
  k2_softmax<<<dim3(1024), dim3(256), 0, stream>>>(out, cst, ws);
  if (use_ws)
    k3_read_ws<<<dim3(4, 16, 32), dim3(256), 0, stream>>>(m_out, out, ws);
  else
    k3_read_fb<<<dim3(4, 16, 16), dim3(256), 0, stream>>>(m_out, out);
}